// Round 6
// baseline (3544.831 us; speedup 1.0000x reference)
//
#include <hip/hip_runtime.h>
#include <hip/hip_bf16.h>

#define B_ 16
#define T_ 12
#define N_ 2000
#define E_ 8000
#define M_ 32000                 // B_*N_
#define ETOT (B_*E_ + M_)        // 160000 edges incl. self loops
#define D_ 64
#define TB_ 4                    // timesteps batched per GAT launch

typedef __hip_bfloat16 bf16;
typedef unsigned short u16;

__device__ __forceinline__ float bfu(u16 u){ return __uint_as_float(((unsigned int)u)<<16); }
__device__ __forceinline__ u16 f2bu(float f){
  unsigned int x = __float_as_uint(f);
  x += 0x7FFFu + ((x >> 16) & 1u);
  return (u16)(x >> 16);
}
__device__ __forceinline__ float wred64(float x){
  x += __shfl_xor(x,1); x += __shfl_xor(x,2); x += __shfl_xor(x,4);
  x += __shfl_xor(x,8); x += __shfl_xor(x,16); x += __shfl_xor(x,32);
  return x;
}

// ---------------- weight prep ----------------
// wqP u16 [L][16][3][64][4]: bf16(Wqkv[l][s*64+j][d4*4+u])      24576
// woP u16 [L][16][64][4]   : bf16(Wo[l][j*64 + d4*4+u])          8192
// W2T f32 [L][128][64]     : Wf2[l][j*128 + hc]                 16384
__global__ void k_prep(const float* __restrict__ Wqkv, const float* __restrict__ Wo,
                       const float* __restrict__ Wf2,
                       u16* __restrict__ wqP, u16* __restrict__ woP, float* __restrict__ W2T){
  int i = blockIdx.x*256 + threadIdx.x;    // 192 blocks -> 49152 threads exactly
  if(i < 24576){
    int l=i/12288, r0=i-l*12288;
    int d4=r0/768, r1=r0-d4*768;
    int s=r1/256, r2=r1-s*256;
    int jj=r2>>2, u=r2&3;
    wqP[i] = f2bu(Wqkv[l*12288 + (s*64+jj)*64 + d4*4+u]);
  } else if(i < 32768){
    int k2=i-24576;
    int l=k2/4096, r0=k2-l*4096;
    int d4=r0/256, r1=r0-d4*256, jj=r1>>2, u=r1&3;
    woP[k2] = f2bu(Wo[l*4096 + jj*64 + d4*4+u]);
  } else {
    int k2=i-32768;
    int l=k2/8192, r0=k2-l*8192;
    int hc=r0>>6, jj=r0&63;
    W2T[k2] = Wf2[l*8192 + jj*128 + hc];
  }
}

// ---------------- CSR build ----------------
__global__ void k_zero(int* __restrict__ p, int n){
  int i = blockIdx.x*256 + threadIdx.x; if(i<n) p[i]=0;
}

__global__ void k_hist(const int* __restrict__ ei, int* __restrict__ deg){
  int e = blockIdx.x*256 + threadIdx.x; if(e>=ETOT) return;
  int dst;
  if (e < B_*E_){ int b = e / E_; int k = e - b*E_; dst = ei[E_ + k] + b*N_; }
  else dst = e - B_*E_;
  atomicAdd(&deg[dst], 1);
}

__global__ void k_scan1(const int* __restrict__ deg, int* __restrict__ offs, int* __restrict__ bsums){
  __shared__ int s[256];
  int tid = threadIdx.x; int g = blockIdx.x*256 + tid;
  s[tid] = deg[g]; __syncthreads();
  for(int off=1; off<256; off<<=1){
    int a = (tid>=off) ? s[tid-off] : 0; __syncthreads();
    s[tid] += a; __syncthreads();
  }
  offs[g+1] = s[tid];
  if(tid==255) bsums[blockIdx.x] = s[255];
}

__global__ void k_scan2(const int* __restrict__ bsums, int* __restrict__ boffs){
  __shared__ int s[128];
  int tid = threadIdx.x;
  int v = (tid<125) ? bsums[tid] : 0;
  s[tid] = v; __syncthreads();
  for(int off=1; off<128; off<<=1){
    int a = (tid>=off) ? s[tid-off] : 0; __syncthreads();
    s[tid] += a; __syncthreads();
  }
  if(tid<125) boffs[tid] = s[tid] - v;
}

__global__ void k_scan3(int* __restrict__ offs, const int* __restrict__ boffs){
  int tid = threadIdx.x; int g = blockIdx.x*256 + tid;
  offs[g+1] += boffs[blockIdx.x];
  if(g==0) offs[0]=0;
}

__global__ void k_scatter(const int* __restrict__ ei, const int* __restrict__ offs,
                          int* __restrict__ cursor, int* __restrict__ csr){
  int e = blockIdx.x*256 + threadIdx.x; if(e>=ETOT) return;
  int src, dst;
  if (e < B_*E_){ int b=e/E_; int k=e-b*E_; src=ei[k]+b*N_; dst=ei[E_+k]+b*N_; }
  else { src = e - B_*E_; dst = src; }
  int pos = atomicAdd(&cursor[dst], 1);
  csr[offs[dst]+pos] = src;
}

// ---------------- fused GAT1 + GAT2 feature/score, batched over TB_ timesteps ----
__global__ __launch_bounds__(256) void k_gat12(
  const float* __restrict__ x_seq, const float* __restrict__ W1,
  const float* __restrict__ as1, const float* __restrict__ ad1, const float* __restrict__ b1,
  const float* __restrict__ W2, const float* __restrict__ as2, const float* __restrict__ ad2,
  const int* __restrict__ offs, const int* __restrict__ csr,
  u16* __restrict__ h2u, float* __restrict__ asc, float* __restrict__ adc, int t0)
{
  __shared__ float W2s[2048];       // [k=32][c=64] fp32
  __shared__ float a2s[64], a2d[64];
  int tid = threadIdx.x;
  for(int i=tid;i<2048;i+=256) W2s[i]=W2[i];
  if(tid<64){ a2s[tid]=as2[tid]; a2d[tid]=ad2[tid]; }
  __syncthreads();

  int tb = blockIdx.y, t = t0 + tb;
  int id = blockIdx.x*256 + tid;     // 500*256 = M_*4
  int m = id>>2, q = id&3;

  float sS[4], sD[4];
  #pragma unroll
  for(int h=0;h<4;h++){
    float a=0.f, d=0.f;
    #pragma unroll
    for(int c=0;c<8;c++){ float w=W1[h*8+c]; a+=w*as1[h*8+c]; d+=w*ad1[h*8+c]; }
    sS[h]=a; sD[h]=d;
  }
  unsigned um=(unsigned)m, b=um/N_, n=um-b*N_;
  const float* xsl = x_seq + (size_t)(b*T_+t)*N_;
  float xm = xsl[n];
  int e0=offs[m], e1=offs[m+1];
  // single-pass softmax (scores are O(1): no overflow risk)
  float sum[4]={0,0,0,0}, ax[4]={0,0,0,0};
  for(int e=e0;e<e1;e++){
    unsigned s=(unsigned)csr[e]; unsigned sn=s - (s/N_)*N_;
    float xv = xsl[sn];
    #pragma unroll
    for(int h=0;h<4;h++){
      float ee = xv*sS[h] + xm*sD[h]; ee = ee>0.f ? ee : 0.2f*ee;
      float w = __expf(ee); sum[h]+=w; ax[h]+=w*xv;
    }
  }
  float A[4];
  #pragma unroll
  for(int h=0;h<4;h++) A[h] = ax[h]/(sum[h]+1e-16f);

  float acc[16];
  #pragma unroll
  for(int c=0;c<16;c++) acc[c]=0.f;
  #pragma unroll
  for(int k=0;k<32;k++){
    int h = k>>3;
    float v = A[h]*W1[k] + b1[k]; v = v>0.f ? v : 0.f;   // relu(out1)
    #pragma unroll
    for(int c=0;c<16;c++) acc[c] += v*W2s[k*64 + q*16 + c];
  }
  // pack bf16, 4x uint2 stores
  uint2* hp = (uint2*)(h2u + ((size_t)tb*M_ + m)*64 + q*16);
  #pragma unroll
  for(int c2=0;c2<4;c2++){
    uint2 p;
    p.x = (unsigned)f2bu(acc[4*c2+0]) | ((unsigned)f2bu(acc[4*c2+1])<<16);
    p.y = (unsigned)f2bu(acc[4*c2+2]) | ((unsigned)f2bu(acc[4*c2+3])<<16);
    hp[c2] = p;
  }
  float ss=0.f, sd=0.f;
  #pragma unroll
  for(int c=0;c<16;c++){ ss += acc[c]*a2s[q*16+c]; sd += acc[c]*a2d[q*16+c]; }
  asc[((size_t)tb*M_+m)*4+q]=ss; adc[((size_t)tb*M_+m)*4+q]=sd;
}

// ---------------- GAT2 softmax-aggregate + bias + relu + PE, batched ----------------
__global__ __launch_bounds__(256) void k_gat2b(
  const u16* __restrict__ h2u, const float* __restrict__ asc, const float* __restrict__ adc,
  const float* __restrict__ b2, const int* __restrict__ offs, const int* __restrict__ csr,
  float* __restrict__ seq, int t0)
{
  int tb = blockIdx.y, t = t0 + tb;
  int id = blockIdx.x*256 + threadIdx.x;
  int m = id>>2, h = id&3;
  float am = adc[((size_t)tb*M_+m)*4+h];
  int e0=offs[m], e1=offs[m+1];
  float sum=0.f;
  float A[16];
  #pragma unroll
  for(int c=0;c<16;c++) A[c]=0.f;
  for(int e=e0;e<e1;e++){
    int s=csr[e];
    float ee = asc[((size_t)tb*M_+s)*4+h] + am; ee = ee>0.f ? ee : 0.2f*ee;
    float w = __expf(ee); sum += w;
    const uint2* hp = (const uint2*)(h2u + ((size_t)tb*M_ + s)*64 + h*16);
    #pragma unroll
    for(int c2=0;c2<4;c2++){
      uint2 p = hp[c2];
      A[4*c2+0] += w*bfu((u16)(p.x));
      A[4*c2+1] += w*bfu((u16)(p.x>>16));
      A[4*c2+2] += w*bfu((u16)(p.y));
      A[4*c2+3] += w*bfu((u16)(p.y>>16));
    }
  }
  float inv = 1.f/(sum + 1e-16f);
  #pragma unroll
  for(int c=0;c<16;c++){
    int ch = h*16 + c;
    float v = A[c]*inv + b2[ch]; v = v>0.f ? v : 0.f;
    float ang = (float)t * __expf(-0.14391156463f * (float)(ch & ~1));  // ln(1e4)/64
    float pe = (ch&1) ? __cosf(ang) : __sinf(ang);
    seq[((size_t)t*M_ + m)*64 + ch] = v + pe;
  }
}

// ---------------- fused attention block: Xs/QKV LDS union, 4 blocks/CU ----------------
__global__ __launch_bounds__(256) void k_attn(
  float* __restrict__ seq,
  const u16* __restrict__ wqP,   // [16][3][64][4] packed bf16
  const u16* __restrict__ woP,   // [16][64][4]    packed bf16
  const float* __restrict__ bqkv, const float* __restrict__ bo,
  const float* __restrict__ g1,   const float* __restrict__ be1)
{
  __shared__ __align__(16) float U[4][2448];   // 39168 B total
  int tid = threadIdx.x, w = tid>>6, j = tid&63;
  int m = blockIdx.x*4 + w;
  float* Uw = U[w];

  float xr[12];
  #pragma unroll
  for(int t=0;t<12;t++){ float x = seq[((size_t)t*M_ + m)*64 + j]; xr[t]=x; Uw[t*64+j]=x; }
  float bqj = bqkv[j], bkj = bqkv[64+j], bvj = bqkv[128+j];
  float boj = bo[j], gj = g1[j], bej = be1[j];
  __syncthreads();

  // phase 1: qkv projection. lane j owns column j of q,k,v for all t.
  float q[12],k[12],v[12];
  #pragma unroll
  for(int t=0;t<12;t++){ q[t]=bqj; k[t]=bkj; v[t]=bvj; }
  const ushort4* wq4 = (const ushort4*)wqP;
  #pragma unroll
  for(int d4=0; d4<16; d4++){
    float4 xv[12];
    #pragma unroll
    for(int t=0;t<12;t++) xv[t] = *(const float4*)&Uw[t*64 + d4*4];
    ushort4 aq = wq4[(d4*3+0)*64 + j];
    ushort4 ak = wq4[(d4*3+1)*64 + j];
    ushort4 av = wq4[(d4*3+2)*64 + j];
    float q0=bfu(aq.x),q1=bfu(aq.y),q2=bfu(aq.z),q3=bfu(aq.w);
    float k0=bfu(ak.x),k1=bfu(ak.y),k2=bfu(ak.z),k3=bfu(ak.w);
    float v0=bfu(av.x),v1=bfu(av.y),v2=bfu(av.z),v3=bfu(av.w);
    #pragma unroll
    for(int t=0;t<12;t++){
      q[t]+=xv[t].x*q0; q[t]+=xv[t].y*q1; q[t]+=xv[t].z*q2; q[t]+=xv[t].w*q3;
      k[t]+=xv[t].x*k0; k[t]+=xv[t].y*k1; k[t]+=xv[t].z*k2; k[t]+=xv[t].w*k3;
      v[t]+=xv[t].x*v0; v[t]+=xv[t].y*v1; v[t]+=xv[t].z*v2; v[t]+=xv[t].w*v3;
    }
  }
  #pragma unroll
  for(int t=0;t<12;t++){
    Uw[       t*68 + j]=q[t];     // QKV[0] overlays Xs — stores depend on all loads
    Uw[ 816 + t*68 + j]=k[t];
    Uw[1632 + t*68 + j]=v[t];
  }
  __syncthreads();

  // phase 2: attention. 48 lanes own (head h, time t); in-register softmax.
  if(j < 48){
    int h = j/12, t = j - h*12;
    float* qrow = &Uw[t*68 + h*16];
    float4 a0=((float4*)qrow)[0], a1=((float4*)qrow)[1], a2=((float4*)qrow)[2], a3=((float4*)qrow)[3];
    float s[12];
    #pragma unroll
    for(int t2=0;t2<12;t2++){
      const float4* kr = (const float4*)&Uw[816 + t2*68 + h*16];
      float4 c0=kr[0], c1=kr[1], c2=kr[2], c3=kr[3];
      float d = a0.x*c0.x + a0.y*c0.y + a0.z*c0.z + a0.w*c0.w
              + a1.x*c1.x + a1.y*c1.y + a1.z*c1.z + a1.w*c1.w
              + a2.x*c2.x + a2.y*c2.y + a2.z*c2.z + a2.w*c2.w
              + a3.x*c3.x + a3.y*c3.y + a3.z*c3.z + a3.w*c3.w;
      s[t2] = d*0.25f;                 // 1/sqrt(16)
    }
    float mx = s[0];
    #pragma unroll
    for(int t2=1;t2<12;t2++) mx = fmaxf(mx, s[t2]);
    float sum = 0.f;
    #pragma unroll
    for(int t2=0;t2<12;t2++){ s[t2]=__expf(s[t2]-mx); sum+=s[t2]; }
    float inv = 1.f/sum;
    float4 o0=make_float4(0,0,0,0), o1=o0, o2=o0, o3=o0;
    #pragma unroll
    for(int t2=0;t2<12;t2++){
      const float4* vr = (const float4*)&Uw[1632 + t2*68 + h*16];
      float4 c0=vr[0], c1=vr[1], c2=vr[2], c3=vr[3];
      float ww = s[t2];
      o0.x+=ww*c0.x; o0.y+=ww*c0.y; o0.z+=ww*c0.z; o0.w+=ww*c0.w;
      o1.x+=ww*c1.x; o1.y+=ww*c1.y; o1.z+=ww*c1.z; o1.w+=ww*c1.w;
      o2.x+=ww*c2.x; o2.y+=ww*c2.y; o2.z+=ww*c2.z; o2.w+=ww*c2.w;
      o3.x+=ww*c3.x; o3.y+=ww*c3.y; o3.z+=ww*c3.z; o3.w+=ww*c3.w;
    }
    o0.x*=inv;o0.y*=inv;o0.z*=inv;o0.w*=inv;
    o1.x*=inv;o1.y*=inv;o1.z*=inv;o1.w*=inv;
    o2.x*=inv;o2.y*=inv;o2.z*=inv;o2.w*=inv;
    o3.x*=inv;o3.y*=inv;o3.z*=inv;o3.w*=inv;
    ((float4*)qrow)[0]=o0; ((float4*)qrow)[1]=o1; ((float4*)qrow)[2]=o2; ((float4*)qrow)[3]=o3;
  }
  __syncthreads();

  // phase 3: Wo + residual + LN (O sits in QKV[0] region)
  float acc[12];
  #pragma unroll
  for(int t=0;t<12;t++) acc[t]=boj;
  const ushort4* wo4 = (const ushort4*)woP;
  #pragma unroll
  for(int d4=0; d4<16; d4++){
    ushort4 aw = wo4[d4*64 + j];
    float w0=bfu(aw.x), w1=bfu(aw.y), w2=bfu(aw.z), w3=bfu(aw.w);
    #pragma unroll
    for(int t=0;t<12;t++){
      float4 ov = *(const float4*)&Uw[t*68 + d4*4];
      acc[t]+=ov.x*w0; acc[t]+=ov.y*w1; acc[t]+=ov.z*w2; acc[t]+=ov.w*w3;
    }
  }
  #pragma unroll
  for(int t=0;t<12;t++){
    float x = xr[t] + acc[t];
    float mu = wred64(x)*(1.f/64.f);
    float dd = x - mu;
    float var = wred64(dd*dd)*(1.f/64.f);
    float y = dd*rsqrtf(var+1e-5f)*gj + bej;
    seq[((size_t)t*M_ + m)*64 + j] = y;
  }
}

// ---------------- FF + residual + LN: 2 threads/row, split hidden dot ----------------
// Lane parity = column half. Each thread holds X[8]/Y[8] float4 (64 floats total,
// provably register-resident). Wf1 dot split across the pair, combined with one
// shfl_xor; LN moments combined with two more. Fully coalesced global access.
__global__ __launch_bounds__(256) void k_ff(
  float* __restrict__ seq,
  const float* __restrict__ Wf1, const float* __restrict__ bf1,
  const float* __restrict__ W2T, const float* __restrict__ bf2,
  const float* __restrict__ g2,  const float* __restrict__ be2)
{
  size_t gid = (size_t)blockIdx.x*256 + threadIdx.x;   // grid 3000 -> 768000 = 2*T*M
  size_t r = gid>>1; int half = (int)(gid&1);
  float* base = seq + r*64 + half*32;

  float4 X[8], Y[8];
  #pragma unroll
  for(int i=0;i<8;i++) X[i] = ((const float4*)base)[i];
  const float4* b24 = (const float4*)(bf2 + half*32);
  #pragma unroll
  for(int i=0;i<8;i++) Y[i] = b24[i];

  #pragma unroll 2
  for(int hc=0;hc<128;hc++){
    const float4* w1 = (const float4*)(Wf1 + hc*64 + half*32);
    float s0=0.f,s1=0.f,s2=0.f,s3=0.f;
    #pragma unroll
    for(int i=0;i<8;i++){
      float4 w=w1[i];
      s0 += X[i].x*w.x; s1 += X[i].y*w.y; s2 += X[i].z*w.z; s3 += X[i].w*w.w;
    }
    float hp = (s0+s1)+(s2+s3);
    float h = hp + __shfl_xor(hp,1) + bf1[hc];
    h = fmaxf(h, 0.f);
    const float4* w2 = (const float4*)(W2T + hc*64 + half*32);
    #pragma unroll
    for(int i=0;i<8;i++){
      float4 w=w2[i];
      Y[i].x += h*w.x; Y[i].y += h*w.y; Y[i].z += h*w.z; Y[i].w += h*w.w;
    }
  }

  // residual + LayerNorm (pair-combined moments)
  float s=0.f;
  #pragma unroll
  for(int i=0;i<8;i++){
    Y[i].x += X[i].x; Y[i].y += X[i].y; Y[i].z += X[i].z; Y[i].w += X[i].w;
    s += (Y[i].x+Y[i].y)+(Y[i].z+Y[i].w);
  }
  s += __shfl_xor(s,1);
  float mu = s*(1.f/64.f);
  float vs=0.f;
  #pragma unroll
  for(int i=0;i<8;i++){
    float dx=Y[i].x-mu, dy=Y[i].y-mu, dz=Y[i].z-mu, dw=Y[i].w-mu;
    vs += (dx*dx+dy*dy)+(dz*dz+dw*dw);
  }
  vs += __shfl_xor(vs,1);
  float sc = rsqrtf(vs*(1.f/64.f)+1e-5f);
  const float4* g4 = (const float4*)(g2 + half*32);
  const float4* e4 = (const float4*)(be2 + half*32);
  #pragma unroll
  for(int i=0;i<8;i++){
    float4 g=g4[i], bb=e4[i], o;
    o.x=(Y[i].x-mu)*sc*g.x+bb.x;
    o.y=(Y[i].y-mu)*sc*g.y+bb.y;
    o.z=(Y[i].z-mu)*sc*g.z+bb.z;
    o.w=(Y[i].w-mu)*sc*g.w+bb.w;
    ((float4*)base)[i]=o;
  }
}

// ---------------- prediction head ----------------
__global__ void k_head(const float* __restrict__ seq, const float* __restrict__ Wh,
                       const float* __restrict__ bh, float* __restrict__ out){
  int m = blockIdx.x*256 + threadIdx.x; if(m>=M_) return;
  const float* row = seq + ((size_t)11*M_ + m)*64;
  float a0=bh[0], a1=bh[1], a2=bh[2];
  #pragma unroll
  for(int d=0;d<64;d++){
    float x = row[d];
    a0 += x*Wh[d]; a1 += x*Wh[64+d]; a2 += x*Wh[128+d];
  }
  unsigned b=(unsigned)m/N_, n=(unsigned)m-b*N_;
  out[(b*3+0)*N_+n] = a0;
  out[(b*3+1)*N_+n] = a1;
  out[(b*3+2)*N_+n] = a2;
}

extern "C" void kernel_launch(void* const* d_in, const int* in_sizes, int n_in,
                              void* d_out, int out_size, void* d_ws, size_t ws_size,
                              hipStream_t stream)
{
  const float* x_seq=(const float*)d_in[0];
  const int*   ei   =(const int*)d_in[1];
  const float* W1   =(const float*)d_in[2];
  const float* as1  =(const float*)d_in[3];
  const float* ad1  =(const float*)d_in[4];
  const float* b1   =(const float*)d_in[5];
  const float* W2   =(const float*)d_in[6];
  const float* as2  =(const float*)d_in[7];
  const float* ad2  =(const float*)d_in[8];
  const float* b2   =(const float*)d_in[9];
  const float* Wqkv =(const float*)d_in[10];
  const float* bqkv =(const float*)d_in[11];
  const float* Wo   =(const float*)d_in[12];
  const float* bo   =(const float*)d_in[13];
  const float* Wf1  =(const float*)d_in[14];
  const float* bf1p =(const float*)d_in[15];
  const float* Wf2  =(const float*)d_in[16];
  const float* bf2p =(const float*)d_in[17];
  const float* g1   =(const float*)d_in[18];
  const float* be1  =(const float*)d_in[19];
  const float* g2   =(const float*)d_in[20];
  const float* be2  =(const float*)d_in[21];
  const float* Wh   =(const float*)d_in[22];
  const float* bh   =(const float*)d_in[23];

  // workspace layout (~120 MB)
  float* seq  = (float*)d_ws;            // [T][M][64]    24,576,000 f
  float* asc  = seq  + 24576000;         // [TB_][M][4]      512,000 f
  float* adc  = asc  + 512000;           //                  512,000 f
  float* W2T  = adc  + 512000;           // [2][128][64]      16,384 f
  int* deg    = (int*)(W2T + 16384);
  int* cursor = deg + M_;
  int* offs   = cursor + M_;             // M_+1 used
  int* bsums  = offs + (M_ + 2);
  int* boffs  = bsums + 128;
  int* csr    = boffs + 128;             // ETOT
  u16* h2u    = (u16*)(csr + ETOT);      // [TB_][M][64]  8,192,000 u16
  u16* wqP    = h2u + (size_t)TB_*M_*64; // 24576
  u16* woP    = wqP + 24576;             // 8192

  k_prep   <<<dim3(192), dim3(256), 0, stream>>>(Wqkv, Wo, Wf2, wqP, woP, W2T);

  // CSR build (edge list identical for all t)
  k_zero   <<<dim3((2*M_+255)/256), dim3(256), 0, stream>>>(deg, 2*M_);
  k_hist   <<<dim3((ETOT+255)/256), dim3(256), 0, stream>>>(ei, deg);
  k_scan1  <<<dim3(125), dim3(256), 0, stream>>>(deg, offs, bsums);
  k_scan2  <<<dim3(1),   dim3(128), 0, stream>>>(bsums, boffs);
  k_scan3  <<<dim3(125), dim3(256), 0, stream>>>(offs, boffs);
  k_scatter<<<dim3((ETOT+255)/256), dim3(256), 0, stream>>>(ei, offs, cursor, csr);

  for(int t0=0; t0<T_; t0+=TB_){
    k_gat12<<<dim3(500,TB_), dim3(256), 0, stream>>>(x_seq, W1, as1, ad1, b1,
                                                     W2, as2, ad2, offs, csr, h2u, asc, adc, t0);
    k_gat2b<<<dim3(500,TB_), dim3(256), 0, stream>>>(h2u, asc, adc, b2, offs, csr, seq, t0);
  }

  for(int i=0;i<2;i++){
    k_attn<<<dim3(8000), dim3(256), 0, stream>>>(seq,
        wqP + (size_t)i*12288, woP + (size_t)i*4096,
        bqkv + (size_t)i*192,  bo   + (size_t)i*64,
        g1   + (size_t)i*64,   be1  + (size_t)i*64);
    k_ff  <<<dim3(3000), dim3(256), 0, stream>>>(seq,
        Wf1  + (size_t)i*8192, bf1p + (size_t)i*128,
        W2T  + (size_t)i*8192, bf2p + (size_t)i*64,
        g2   + (size_t)i*64,   be2  + (size_t)i*64);
  }

  k_head<<<dim3(125), dim3(256), 0, stream>>>(seq, Wh, bh, (float*)d_out);
}

// Round 7
// 1639.444 us; speedup vs baseline: 2.1622x; 2.1622x over previous
//
#include <hip/hip_runtime.h>
#include <hip/hip_bf16.h>

#define B_ 16
#define T_ 12
#define N_ 2000
#define E_ 8000
#define M_ 32000                 // B_*N_
#define ETOT (B_*E_ + M_)        // 160000 edges incl. self loops
#define D_ 64
#define TB_ 4                    // timesteps batched per GAT launch

typedef __hip_bfloat16 bf16;
typedef unsigned short u16;

__device__ __forceinline__ float bfu(u16 u){ return __uint_as_float(((unsigned int)u)<<16); }
__device__ __forceinline__ u16 f2bu(float f){
  unsigned int x = __float_as_uint(f);
  x += 0x7FFFu + ((x >> 16) & 1u);
  return (u16)(x >> 16);
}
__device__ __forceinline__ float wred64(float x){
  x += __shfl_xor(x,1); x += __shfl_xor(x,2); x += __shfl_xor(x,4);
  x += __shfl_xor(x,8); x += __shfl_xor(x,16); x += __shfl_xor(x,32);
  return x;
}

// ---------------- weight prep ----------------
// wqP u16 [L][16][3][64][4]: bf16(Wqkv[l][s*64+j][d4*4+u])      24576
// woP u16 [L][16][64][4]   : bf16(Wo[l][j*64 + d4*4+u])          8192
// W2T f32 [L][128][64]     : Wf2[l][j*128 + hc]                 16384
__global__ void k_prep(const float* __restrict__ Wqkv, const float* __restrict__ Wo,
                       const float* __restrict__ Wf2,
                       u16* __restrict__ wqP, u16* __restrict__ woP, float* __restrict__ W2T){
  int i = blockIdx.x*256 + threadIdx.x;    // 192 blocks -> 49152 threads exactly
  if(i < 24576){
    int l=i/12288, r0=i-l*12288;
    int d4=r0/768, r1=r0-d4*768;
    int s=r1/256, r2=r1-s*256;
    int jj=r2>>2, u=r2&3;
    wqP[i] = f2bu(Wqkv[l*12288 + (s*64+jj)*64 + d4*4+u]);
  } else if(i < 32768){
    int k2=i-24576;
    int l=k2/4096, r0=k2-l*4096;
    int d4=r0/256, r1=r0-d4*256, jj=r1>>2, u=r1&3;
    woP[k2] = f2bu(Wo[l*4096 + jj*64 + d4*4+u]);
  } else {
    int k2=i-32768;
    int l=k2/8192, r0=k2-l*8192;
    int hc=r0>>6, jj=r0&63;
    W2T[k2] = Wf2[l*8192 + jj*128 + hc];
  }
}

// ---------------- CSR build ----------------
__global__ void k_zero(int* __restrict__ p, int n){
  int i = blockIdx.x*256 + threadIdx.x; if(i<n) p[i]=0;
}

__global__ void k_hist(const int* __restrict__ ei, int* __restrict__ deg){
  int e = blockIdx.x*256 + threadIdx.x; if(e>=ETOT) return;
  int dst;
  if (e < B_*E_){ int b = e / E_; int k = e - b*E_; dst = ei[E_ + k] + b*N_; }
  else dst = e - B_*E_;
  atomicAdd(&deg[dst], 1);
}

__global__ void k_scan1(const int* __restrict__ deg, int* __restrict__ offs, int* __restrict__ bsums){
  __shared__ int s[256];
  int tid = threadIdx.x; int g = blockIdx.x*256 + tid;
  s[tid] = deg[g]; __syncthreads();
  for(int off=1; off<256; off<<=1){
    int a = (tid>=off) ? s[tid-off] : 0; __syncthreads();
    s[tid] += a; __syncthreads();
  }
  offs[g+1] = s[tid];
  if(tid==255) bsums[blockIdx.x] = s[255];
}

__global__ void k_scan2(const int* __restrict__ bsums, int* __restrict__ boffs){
  __shared__ int s[128];
  int tid = threadIdx.x;
  int v = (tid<125) ? bsums[tid] : 0;
  s[tid] = v; __syncthreads();
  for(int off=1; off<128; off<<=1){
    int a = (tid>=off) ? s[tid-off] : 0; __syncthreads();
    s[tid] += a; __syncthreads();
  }
  if(tid<125) boffs[tid] = s[tid] - v;
}

__global__ void k_scan3(int* __restrict__ offs, const int* __restrict__ boffs){
  int tid = threadIdx.x; int g = blockIdx.x*256 + tid;
  offs[g+1] += boffs[blockIdx.x];
  if(g==0) offs[0]=0;
}

__global__ void k_scatter(const int* __restrict__ ei, const int* __restrict__ offs,
                          int* __restrict__ cursor, int* __restrict__ csr){
  int e = blockIdx.x*256 + threadIdx.x; if(e>=ETOT) return;
  int src, dst;
  if (e < B_*E_){ int b=e/E_; int k=e-b*E_; src=ei[k]+b*N_; dst=ei[E_+k]+b*N_; }
  else { src = e - B_*E_; dst = src; }
  int pos = atomicAdd(&cursor[dst], 1);
  csr[offs[dst]+pos] = src;
}

// ---------------- fused GAT1 + GAT2 feature/score, batched over TB_ timesteps ----
__global__ __launch_bounds__(256) void k_gat12(
  const float* __restrict__ x_seq, const float* __restrict__ W1,
  const float* __restrict__ as1, const float* __restrict__ ad1, const float* __restrict__ b1,
  const float* __restrict__ W2, const float* __restrict__ as2, const float* __restrict__ ad2,
  const int* __restrict__ offs, const int* __restrict__ csr,
  u16* __restrict__ h2u, float* __restrict__ asc, float* __restrict__ adc, int t0)
{
  __shared__ float W2s[2048];       // [k=32][c=64] fp32
  __shared__ float a2s[64], a2d[64];
  int tid = threadIdx.x;
  for(int i=tid;i<2048;i+=256) W2s[i]=W2[i];
  if(tid<64){ a2s[tid]=as2[tid]; a2d[tid]=ad2[tid]; }
  __syncthreads();

  int tb = blockIdx.y, t = t0 + tb;
  int id = blockIdx.x*256 + tid;     // 500*256 = M_*4
  int m = id>>2, q = id&3;

  float sS[4], sD[4];
  #pragma unroll
  for(int h=0;h<4;h++){
    float a=0.f, d=0.f;
    #pragma unroll
    for(int c=0;c<8;c++){ float w=W1[h*8+c]; a+=w*as1[h*8+c]; d+=w*ad1[h*8+c]; }
    sS[h]=a; sD[h]=d;
  }
  unsigned um=(unsigned)m, b=um/N_, n=um-b*N_;
  const float* xsl = x_seq + (size_t)(b*T_+t)*N_;
  float xm = xsl[n];
  int e0=offs[m], e1=offs[m+1];
  // single-pass softmax (scores are O(1): no overflow risk)
  float sum[4]={0,0,0,0}, ax[4]={0,0,0,0};
  for(int e=e0;e<e1;e++){
    unsigned s=(unsigned)csr[e]; unsigned sn=s - (s/N_)*N_;
    float xv = xsl[sn];
    #pragma unroll
    for(int h=0;h<4;h++){
      float ee = xv*sS[h] + xm*sD[h]; ee = ee>0.f ? ee : 0.2f*ee;
      float w = __expf(ee); sum[h]+=w; ax[h]+=w*xv;
    }
  }
  float A[4];
  #pragma unroll
  for(int h=0;h<4;h++) A[h] = ax[h]/(sum[h]+1e-16f);

  float acc[16];
  #pragma unroll
  for(int c=0;c<16;c++) acc[c]=0.f;
  #pragma unroll
  for(int k=0;k<32;k++){
    int h = k>>3;
    float v = A[h]*W1[k] + b1[k]; v = v>0.f ? v : 0.f;   // relu(out1)
    #pragma unroll
    for(int c=0;c<16;c++) acc[c] += v*W2s[k*64 + q*16 + c];
  }
  // pack bf16, 4x uint2 stores
  uint2* hp = (uint2*)(h2u + ((size_t)tb*M_ + m)*64 + q*16);
  #pragma unroll
  for(int c2=0;c2<4;c2++){
    uint2 p;
    p.x = (unsigned)f2bu(acc[4*c2+0]) | ((unsigned)f2bu(acc[4*c2+1])<<16);
    p.y = (unsigned)f2bu(acc[4*c2+2]) | ((unsigned)f2bu(acc[4*c2+3])<<16);
    hp[c2] = p;
  }
  float ss=0.f, sd=0.f;
  #pragma unroll
  for(int c=0;c<16;c++){ ss += acc[c]*a2s[q*16+c]; sd += acc[c]*a2d[q*16+c]; }
  asc[((size_t)tb*M_+m)*4+q]=ss; adc[((size_t)tb*M_+m)*4+q]=sd;
}

// ---------------- GAT2 softmax-aggregate + bias + relu + PE, batched ----------------
__global__ __launch_bounds__(256) void k_gat2b(
  const u16* __restrict__ h2u, const float* __restrict__ asc, const float* __restrict__ adc,
  const float* __restrict__ b2, const int* __restrict__ offs, const int* __restrict__ csr,
  float* __restrict__ seq, int t0)
{
  int tb = blockIdx.y, t = t0 + tb;
  int id = blockIdx.x*256 + threadIdx.x;
  int m = id>>2, h = id&3;
  float am = adc[((size_t)tb*M_+m)*4+h];
  int e0=offs[m], e1=offs[m+1];
  float sum=0.f;
  float A[16];
  #pragma unroll
  for(int c=0;c<16;c++) A[c]=0.f;
  for(int e=e0;e<e1;e++){
    int s=csr[e];
    float ee = asc[((size_t)tb*M_+s)*4+h] + am; ee = ee>0.f ? ee : 0.2f*ee;
    float w = __expf(ee); sum += w;
    const uint2* hp = (const uint2*)(h2u + ((size_t)tb*M_ + s)*64 + h*16);
    #pragma unroll
    for(int c2=0;c2<4;c2++){
      uint2 p = hp[c2];
      A[4*c2+0] += w*bfu((u16)(p.x));
      A[4*c2+1] += w*bfu((u16)(p.x>>16));
      A[4*c2+2] += w*bfu((u16)(p.y));
      A[4*c2+3] += w*bfu((u16)(p.y>>16));
    }
  }
  float inv = 1.f/(sum + 1e-16f);
  #pragma unroll
  for(int c=0;c<16;c++){
    int ch = h*16 + c;
    float v = A[c]*inv + b2[ch]; v = v>0.f ? v : 0.f;
    float ang = (float)t * __expf(-0.14391156463f * (float)(ch & ~1));  // ln(1e4)/64
    float pe = (ch&1) ? __cosf(ang) : __sinf(ang);
    seq[((size_t)t*M_ + m)*64 + ch] = v + pe;
  }
}

// ---------------- fused attention block: Xs/QKV LDS union, 4 blocks/CU ----------------
__global__ __launch_bounds__(256) void k_attn(
  float* __restrict__ seq,
  const u16* __restrict__ wqP,   // [16][3][64][4] packed bf16
  const u16* __restrict__ woP,   // [16][64][4]    packed bf16
  const float* __restrict__ bqkv, const float* __restrict__ bo,
  const float* __restrict__ g1,   const float* __restrict__ be1)
{
  __shared__ __align__(16) float U[4][2448];   // 39168 B total
  int tid = threadIdx.x, w = tid>>6, j = tid&63;
  int m = blockIdx.x*4 + w;
  float* Uw = U[w];

  float xr[12];
  #pragma unroll
  for(int t=0;t<12;t++){ float x = seq[((size_t)t*M_ + m)*64 + j]; xr[t]=x; Uw[t*64+j]=x; }
  float bqj = bqkv[j], bkj = bqkv[64+j], bvj = bqkv[128+j];
  float boj = bo[j], gj = g1[j], bej = be1[j];
  __syncthreads();

  // phase 1: qkv projection. lane j owns column j of q,k,v for all t.
  float q[12],k[12],v[12];
  #pragma unroll
  for(int t=0;t<12;t++){ q[t]=bqj; k[t]=bkj; v[t]=bvj; }
  const ushort4* wq4 = (const ushort4*)wqP;
  #pragma unroll
  for(int d4=0; d4<16; d4++){
    float4 xv[12];
    #pragma unroll
    for(int t=0;t<12;t++) xv[t] = *(const float4*)&Uw[t*64 + d4*4];
    ushort4 aq = wq4[(d4*3+0)*64 + j];
    ushort4 ak = wq4[(d4*3+1)*64 + j];
    ushort4 av = wq4[(d4*3+2)*64 + j];
    float q0=bfu(aq.x),q1=bfu(aq.y),q2=bfu(aq.z),q3=bfu(aq.w);
    float k0=bfu(ak.x),k1=bfu(ak.y),k2=bfu(ak.z),k3=bfu(ak.w);
    float v0=bfu(av.x),v1=bfu(av.y),v2=bfu(av.z),v3=bfu(av.w);
    #pragma unroll
    for(int t=0;t<12;t++){
      q[t]+=xv[t].x*q0; q[t]+=xv[t].y*q1; q[t]+=xv[t].z*q2; q[t]+=xv[t].w*q3;
      k[t]+=xv[t].x*k0; k[t]+=xv[t].y*k1; k[t]+=xv[t].z*k2; k[t]+=xv[t].w*k3;
      v[t]+=xv[t].x*v0; v[t]+=xv[t].y*v1; v[t]+=xv[t].z*v2; v[t]+=xv[t].w*v3;
    }
  }
  #pragma unroll
  for(int t=0;t<12;t++){
    Uw[       t*68 + j]=q[t];     // QKV[0] overlays Xs — stores depend on all loads
    Uw[ 816 + t*68 + j]=k[t];
    Uw[1632 + t*68 + j]=v[t];
  }
  __syncthreads();

  // phase 2: attention. 48 lanes own (head h, time t); in-register softmax.
  if(j < 48){
    int h = j/12, t = j - h*12;
    float* qrow = &Uw[t*68 + h*16];
    float4 a0=((float4*)qrow)[0], a1=((float4*)qrow)[1], a2=((float4*)qrow)[2], a3=((float4*)qrow)[3];
    float s[12];
    #pragma unroll
    for(int t2=0;t2<12;t2++){
      const float4* kr = (const float4*)&Uw[816 + t2*68 + h*16];
      float4 c0=kr[0], c1=kr[1], c2=kr[2], c3=kr[3];
      float d = a0.x*c0.x + a0.y*c0.y + a0.z*c0.z + a0.w*c0.w
              + a1.x*c1.x + a1.y*c1.y + a1.z*c1.z + a1.w*c1.w
              + a2.x*c2.x + a2.y*c2.y + a2.z*c2.z + a2.w*c2.w
              + a3.x*c3.x + a3.y*c3.y + a3.z*c3.z + a3.w*c3.w;
      s[t2] = d*0.25f;                 // 1/sqrt(16)
    }
    float mx = s[0];
    #pragma unroll
    for(int t2=1;t2<12;t2++) mx = fmaxf(mx, s[t2]);
    float sum = 0.f;
    #pragma unroll
    for(int t2=0;t2<12;t2++){ s[t2]=__expf(s[t2]-mx); sum+=s[t2]; }
    float inv = 1.f/sum;
    float4 o0=make_float4(0,0,0,0), o1=o0, o2=o0, o3=o0;
    #pragma unroll
    for(int t2=0;t2<12;t2++){
      const float4* vr = (const float4*)&Uw[1632 + t2*68 + h*16];
      float4 c0=vr[0], c1=vr[1], c2=vr[2], c3=vr[3];
      float ww = s[t2];
      o0.x+=ww*c0.x; o0.y+=ww*c0.y; o0.z+=ww*c0.z; o0.w+=ww*c0.w;
      o1.x+=ww*c1.x; o1.y+=ww*c1.y; o1.z+=ww*c1.z; o1.w+=ww*c1.w;
      o2.x+=ww*c2.x; o2.y+=ww*c2.y; o2.z+=ww*c2.z; o2.w+=ww*c2.w;
      o3.x+=ww*c3.x; o3.y+=ww*c3.y; o3.z+=ww*c3.z; o3.w+=ww*c3.w;
    }
    o0.x*=inv;o0.y*=inv;o0.z*=inv;o0.w*=inv;
    o1.x*=inv;o1.y*=inv;o1.z*=inv;o1.w*=inv;
    o2.x*=inv;o2.y*=inv;o2.z*=inv;o2.w*=inv;
    o3.x*=inv;o3.y*=inv;o3.z*=inv;o3.w*=inv;
    ((float4*)qrow)[0]=o0; ((float4*)qrow)[1]=o1; ((float4*)qrow)[2]=o2; ((float4*)qrow)[3]=o3;
  }
  __syncthreads();

  // phase 3: Wo + residual + LN (O sits in QKV[0] region)
  float acc[12];
  #pragma unroll
  for(int t=0;t<12;t++) acc[t]=boj;
  const ushort4* wo4 = (const ushort4*)woP;
  #pragma unroll
  for(int d4=0; d4<16; d4++){
    ushort4 aw = wo4[d4*64 + j];
    float w0=bfu(aw.x), w1=bfu(aw.y), w2=bfu(aw.z), w3=bfu(aw.w);
    #pragma unroll
    for(int t=0;t<12;t++){
      float4 ov = *(const float4*)&Uw[t*68 + d4*4];
      acc[t]+=ov.x*w0; acc[t]+=ov.y*w1; acc[t]+=ov.z*w2; acc[t]+=ov.w*w3;
    }
  }
  #pragma unroll
  for(int t=0;t<12;t++){
    float x = xr[t] + acc[t];
    float mu = wred64(x)*(1.f/64.f);
    float dd = x - mu;
    float var = wred64(dd*dd)*(1.f/64.f);
    float y = dd*rsqrtf(var+1e-5f)*gj + bej;
    seq[((size_t)t*M_ + m)*64 + j] = y;
  }
}

// ---------------- FF + residual + LN: lane-per-row, scalar-pipe weights, ----------
// explicit float4 X[16]/Y[16] register arrays (proven-promotable pattern).
// Weight addresses are wave-uniform -> s_load broadcasts; zero cross-lane ops.
__global__ __launch_bounds__(256) void k_ff(
  float* __restrict__ seq,
  const float* __restrict__ Wf1, const float* __restrict__ bf1,
  const float* __restrict__ W2T, const float* __restrict__ bf2,
  const float* __restrict__ g2,  const float* __restrict__ be2)
{
  size_t r = (size_t)blockIdx.x*256 + threadIdx.x;   // row id; grid=1500 -> 384000 rows
  float* base = seq + r*64;

  float4 X[16], Y[16];
  #pragma unroll
  for(int i=0;i<16;i++) X[i] = ((const float4*)base)[i];
  const float4* b24 = (const float4*)bf2;
  #pragma unroll
  for(int i=0;i<16;i++) Y[i] = b24[i];

  #pragma unroll 2
  for(int hc=0;hc<128;hc++){
    const float4* w1 = (const float4*)(Wf1 + hc*64);   // wave-uniform -> s_load
    float s0=0.f,s1=0.f,s2=0.f,s3=0.f;
    #pragma unroll
    for(int i=0;i<16;i++){
      float4 w=w1[i];
      s0 += X[i].x*w.x; s1 += X[i].y*w.y; s2 += X[i].z*w.z; s3 += X[i].w*w.w;
    }
    float h = (s0+s1)+(s2+s3) + bf1[hc];
    h = fmaxf(h, 0.f);
    const float4* w2 = (const float4*)(W2T + hc*64);   // wave-uniform -> s_load
    #pragma unroll
    for(int i=0;i<16;i++){
      float4 w=w2[i];
      Y[i].x += h*w.x; Y[i].y += h*w.y; Y[i].z += h*w.z; Y[i].w += h*w.w;
    }
  }

  // residual + LayerNorm fully in-lane
  float s=0.f;
  #pragma unroll
  for(int i=0;i<16;i++){
    Y[i].x += X[i].x; Y[i].y += X[i].y; Y[i].z += X[i].z; Y[i].w += X[i].w;
    s += (Y[i].x+Y[i].y)+(Y[i].z+Y[i].w);
  }
  float mu = s*(1.f/64.f);
  float vs=0.f;
  #pragma unroll
  for(int i=0;i<16;i++){
    float dx=Y[i].x-mu, dy=Y[i].y-mu, dz=Y[i].z-mu, dw=Y[i].w-mu;
    vs += (dx*dx+dy*dy)+(dz*dz+dw*dw);
  }
  float sc = rsqrtf(vs*(1.f/64.f)+1e-5f);
  const float4* g4 = (const float4*)g2;
  const float4* e4 = (const float4*)be2;
  #pragma unroll
  for(int i=0;i<16;i++){
    float4 g=g4[i], bb=e4[i], o;
    o.x=(Y[i].x-mu)*sc*g.x+bb.x;
    o.y=(Y[i].y-mu)*sc*g.y+bb.y;
    o.z=(Y[i].z-mu)*sc*g.z+bb.z;
    o.w=(Y[i].w-mu)*sc*g.w+bb.w;
    ((float4*)base)[i]=o;
  }
}

// ---------------- prediction head ----------------
__global__ void k_head(const float* __restrict__ seq, const float* __restrict__ Wh,
                       const float* __restrict__ bh, float* __restrict__ out){
  int m = blockIdx.x*256 + threadIdx.x; if(m>=M_) return;
  const float* row = seq + ((size_t)11*M_ + m)*64;
  float a0=bh[0], a1=bh[1], a2=bh[2];
  #pragma unroll
  for(int d=0;d<64;d++){
    float x = row[d];
    a0 += x*Wh[d]; a1 += x*Wh[64+d]; a2 += x*Wh[128+d];
  }
  unsigned b=(unsigned)m/N_, n=(unsigned)m-b*N_;
  out[(b*3+0)*N_+n] = a0;
  out[(b*3+1)*N_+n] = a1;
  out[(b*3+2)*N_+n] = a2;
}

extern "C" void kernel_launch(void* const* d_in, const int* in_sizes, int n_in,
                              void* d_out, int out_size, void* d_ws, size_t ws_size,
                              hipStream_t stream)
{
  const float* x_seq=(const float*)d_in[0];
  const int*   ei   =(const int*)d_in[1];
  const float* W1   =(const float*)d_in[2];
  const float* as1  =(const float*)d_in[3];
  const float* ad1  =(const float*)d_in[4];
  const float* b1   =(const float*)d_in[5];
  const float* W2   =(const float*)d_in[6];
  const float* as2  =(const float*)d_in[7];
  const float* ad2  =(const float*)d_in[8];
  const float* b2   =(const float*)d_in[9];
  const float* Wqkv =(const float*)d_in[10];
  const float* bqkv =(const float*)d_in[11];
  const float* Wo   =(const float*)d_in[12];
  const float* bo   =(const float*)d_in[13];
  const float* Wf1  =(const float*)d_in[14];
  const float* bf1p =(const float*)d_in[15];
  const float* Wf2  =(const float*)d_in[16];
  const float* bf2p =(const float*)d_in[17];
  const float* g1   =(const float*)d_in[18];
  const float* be1  =(const float*)d_in[19];
  const float* g2   =(const float*)d_in[20];
  const float* be2  =(const float*)d_in[21];
  const float* Wh   =(const float*)d_in[22];
  const float* bh   =(const float*)d_in[23];

  // workspace layout (~120 MB)
  float* seq  = (float*)d_ws;            // [T][M][64]    24,576,000 f
  float* asc  = seq  + 24576000;         // [TB_][M][4]      512,000 f
  float* adc  = asc  + 512000;           //                  512,000 f
  float* W2T  = adc  + 512000;           // [2][128][64]      16,384 f
  int* deg    = (int*)(W2T + 16384);
  int* cursor = deg + M_;
  int* offs   = cursor + M_;             // M_+1 used
  int* bsums  = offs + (M_ + 2);
  int* boffs  = bsums + 128;
  int* csr    = boffs + 128;             // ETOT
  u16* h2u    = (u16*)(csr + ETOT);      // [TB_][M][64]  8,192,000 u16
  u16* wqP    = h2u + (size_t)TB_*M_*64; // 24576
  u16* woP    = wqP + 24576;             // 8192

  k_prep   <<<dim3(192), dim3(256), 0, stream>>>(Wqkv, Wo, Wf2, wqP, woP, W2T);

  // CSR build (edge list identical for all t)
  k_zero   <<<dim3((2*M_+255)/256), dim3(256), 0, stream>>>(deg, 2*M_);
  k_hist   <<<dim3((ETOT+255)/256), dim3(256), 0, stream>>>(ei, deg);
  k_scan1  <<<dim3(125), dim3(256), 0, stream>>>(deg, offs, bsums);
  k_scan2  <<<dim3(1),   dim3(128), 0, stream>>>(bsums, boffs);
  k_scan3  <<<dim3(125), dim3(256), 0, stream>>>(offs, boffs);
  k_scatter<<<dim3((ETOT+255)/256), dim3(256), 0, stream>>>(ei, offs, cursor, csr);

  for(int t0=0; t0<T_; t0+=TB_){
    k_gat12<<<dim3(500,TB_), dim3(256), 0, stream>>>(x_seq, W1, as1, ad1, b1,
                                                     W2, as2, ad2, offs, csr, h2u, asc, adc, t0);
    k_gat2b<<<dim3(500,TB_), dim3(256), 0, stream>>>(h2u, asc, adc, b2, offs, csr, seq, t0);
  }

  for(int i=0;i<2;i++){
    k_attn<<<dim3(8000), dim3(256), 0, stream>>>(seq,
        wqP + (size_t)i*12288, woP + (size_t)i*4096,
        bqkv + (size_t)i*192,  bo   + (size_t)i*64,
        g1   + (size_t)i*64,   be1  + (size_t)i*64);
    k_ff  <<<dim3(1500), dim3(256), 0, stream>>>(seq,
        Wf1  + (size_t)i*8192, bf1p + (size_t)i*128,
        W2T  + (size_t)i*8192, bf2p + (size_t)i*64,
        g2   + (size_t)i*64,   be2  + (size_t)i*64);
  }

  k_head<<<dim3(125), dim3(256), 0, stream>>>(seq, Wh, bh, (float*)d_out);
}

// Round 8
// 1455.341 us; speedup vs baseline: 2.4357x; 1.1265x over previous
//
#include <hip/hip_runtime.h>
#include <hip/hip_bf16.h>

#define B_ 16
#define T_ 12
#define N_ 2000
#define E_ 8000
#define M_ 32000                 // B_*N_
#define ETOT (B_*E_ + M_)        // 160000 edges incl. self loops
#define D_ 64
#define TB_ 4                    // timesteps batched per GAT launch

typedef __hip_bfloat16 bf16;
typedef unsigned short u16;

__device__ __forceinline__ float bfu(u16 u){ return __uint_as_float(((unsigned int)u)<<16); }
__device__ __forceinline__ u16 f2bu(float f){
  unsigned int x = __float_as_uint(f);
  x += 0x7FFFu + ((x >> 16) & 1u);
  return (u16)(x >> 16);
}
__device__ __forceinline__ float wred64(float x){
  x += __shfl_xor(x,1); x += __shfl_xor(x,2); x += __shfl_xor(x,4);
  x += __shfl_xor(x,8); x += __shfl_xor(x,16); x += __shfl_xor(x,32);
  return x;
}

// ---------------- weight prep ----------------
// wqP u16 [L][16][3][64][4]: bf16(Wqkv[l][s*64+j][d4*4+u])      24576
// woP u16 [L][16][64][4]   : bf16(Wo[l][j*64 + d4*4+u])          8192
// W12 f32 [L][128][128]    : [hc][0:64)=Wf1[l][hc][:], [hc][64+j]=Wf2[l][j][hc]   32768
__global__ void k_prep(const float* __restrict__ Wqkv, const float* __restrict__ Wo,
                       const float* __restrict__ Wf1, const float* __restrict__ Wf2,
                       u16* __restrict__ wqP, u16* __restrict__ woP, float* __restrict__ W12){
  int i = blockIdx.x*256 + threadIdx.x;    // 256 blocks -> 65536 threads exactly
  if(i < 24576){
    int l=i/12288, r0=i-l*12288;
    int d4=r0/768, r1=r0-d4*768;
    int s=r1/256, r2=r1-s*256;
    int jj=r2>>2, u=r2&3;
    wqP[i] = f2bu(Wqkv[l*12288 + (s*64+jj)*64 + d4*4+u]);
  } else if(i < 32768){
    int k2=i-24576;
    int l=k2/4096, r0=k2-l*4096;
    int d4=r0/256, r1=r0-d4*256, jj=r1>>2, u=r1&3;
    woP[k2] = f2bu(Wo[l*4096 + jj*64 + d4*4+u]);
  } else {
    int k2=i-32768;                       // [0, 32768)
    int l=k2/16384, r0=k2-l*16384;
    int hc=r0>>7, c=r0&127;
    float v;
    if(c < 64) v = Wf1[l*8192 + hc*64 + c];
    else       v = Wf2[l*8192 + (c-64)*128 + hc];
    W12[k2] = v;
  }
}

// ---------------- CSR build ----------------
__global__ void k_zero(int* __restrict__ p, int n){
  int i = blockIdx.x*256 + threadIdx.x; if(i<n) p[i]=0;
}

__global__ void k_hist(const int* __restrict__ ei, int* __restrict__ deg){
  int e = blockIdx.x*256 + threadIdx.x; if(e>=ETOT) return;
  int dst;
  if (e < B_*E_){ int b = e / E_; int k = e - b*E_; dst = ei[E_ + k] + b*N_; }
  else dst = e - B_*E_;
  atomicAdd(&deg[dst], 1);
}

__global__ void k_scan1(const int* __restrict__ deg, int* __restrict__ offs, int* __restrict__ bsums){
  __shared__ int s[256];
  int tid = threadIdx.x; int g = blockIdx.x*256 + tid;
  s[tid] = deg[g]; __syncthreads();
  for(int off=1; off<256; off<<=1){
    int a = (tid>=off) ? s[tid-off] : 0; __syncthreads();
    s[tid] += a; __syncthreads();
  }
  offs[g+1] = s[tid];
  if(tid==255) bsums[blockIdx.x] = s[255];
}

__global__ void k_scan2(const int* __restrict__ bsums, int* __restrict__ boffs){
  __shared__ int s[128];
  int tid = threadIdx.x;
  int v = (tid<125) ? bsums[tid] : 0;
  s[tid] = v; __syncthreads();
  for(int off=1; off<128; off<<=1){
    int a = (tid>=off) ? s[tid-off] : 0; __syncthreads();
    s[tid] += a; __syncthreads();
  }
  if(tid<125) boffs[tid] = s[tid] - v;
}

__global__ void k_scan3(int* __restrict__ offs, const int* __restrict__ boffs){
  int tid = threadIdx.x; int g = blockIdx.x*256 + tid;
  offs[g+1] += boffs[blockIdx.x];
  if(g==0) offs[0]=0;
}

__global__ void k_scatter(const int* __restrict__ ei, const int* __restrict__ offs,
                          int* __restrict__ cursor, int* __restrict__ csr){
  int e = blockIdx.x*256 + threadIdx.x; if(e>=ETOT) return;
  int src, dst;
  if (e < B_*E_){ int b=e/E_; int k=e-b*E_; src=ei[k]+b*N_; dst=ei[E_+k]+b*N_; }
  else { src = e - B_*E_; dst = src; }
  int pos = atomicAdd(&cursor[dst], 1);
  csr[offs[dst]+pos] = src;
}

// ---------------- fused GAT1 + GAT2 feature/score, batched over TB_ timesteps ----
__global__ __launch_bounds__(256) void k_gat12(
  const float* __restrict__ x_seq, const float* __restrict__ W1,
  const float* __restrict__ as1, const float* __restrict__ ad1, const float* __restrict__ b1,
  const float* __restrict__ W2, const float* __restrict__ as2, const float* __restrict__ ad2,
  const int* __restrict__ offs, const int* __restrict__ csr,
  u16* __restrict__ h2u, float* __restrict__ asc, float* __restrict__ adc, int t0)
{
  __shared__ float W2s[2048];       // [k=32][c=64] fp32
  __shared__ float a2s[64], a2d[64];
  int tid = threadIdx.x;
  for(int i=tid;i<2048;i+=256) W2s[i]=W2[i];
  if(tid<64){ a2s[tid]=as2[tid]; a2d[tid]=ad2[tid]; }
  __syncthreads();

  int tb = blockIdx.y, t = t0 + tb;
  int id = blockIdx.x*256 + tid;     // 500*256 = M_*4
  int m = id>>2, q = id&3;

  float sS[4], sD[4];
  #pragma unroll
  for(int h=0;h<4;h++){
    float a=0.f, d=0.f;
    #pragma unroll
    for(int c=0;c<8;c++){ float w=W1[h*8+c]; a+=w*as1[h*8+c]; d+=w*ad1[h*8+c]; }
    sS[h]=a; sD[h]=d;
  }
  unsigned um=(unsigned)m, b=um/N_, n=um-b*N_;
  const float* xsl = x_seq + (size_t)(b*T_+t)*N_;
  float xm = xsl[n];
  int e0=offs[m], e1=offs[m+1];
  // single-pass softmax (scores are O(1): no overflow risk)
  float sum[4]={0,0,0,0}, ax[4]={0,0,0,0};
  for(int e=e0;e<e1;e++){
    unsigned s=(unsigned)csr[e]; unsigned sn=s - (s/N_)*N_;
    float xv = xsl[sn];
    #pragma unroll
    for(int h=0;h<4;h++){
      float ee = xv*sS[h] + xm*sD[h]; ee = ee>0.f ? ee : 0.2f*ee;
      float w = __expf(ee); sum[h]+=w; ax[h]+=w*xv;
    }
  }
  float A[4];
  #pragma unroll
  for(int h=0;h<4;h++) A[h] = ax[h]/(sum[h]+1e-16f);

  float acc[16];
  #pragma unroll
  for(int c=0;c<16;c++) acc[c]=0.f;
  #pragma unroll
  for(int k=0;k<32;k++){
    int h = k>>3;
    float v = A[h]*W1[k] + b1[k]; v = v>0.f ? v : 0.f;   // relu(out1)
    #pragma unroll
    for(int c=0;c<16;c++) acc[c] += v*W2s[k*64 + q*16 + c];
  }
  // pack bf16, 4x uint2 stores
  uint2* hp = (uint2*)(h2u + ((size_t)tb*M_ + m)*64 + q*16);
  #pragma unroll
  for(int c2=0;c2<4;c2++){
    uint2 p;
    p.x = (unsigned)f2bu(acc[4*c2+0]) | ((unsigned)f2bu(acc[4*c2+1])<<16);
    p.y = (unsigned)f2bu(acc[4*c2+2]) | ((unsigned)f2bu(acc[4*c2+3])<<16);
    hp[c2] = p;
  }
  float ss=0.f, sd=0.f;
  #pragma unroll
  for(int c=0;c<16;c++){ ss += acc[c]*a2s[q*16+c]; sd += acc[c]*a2d[q*16+c]; }
  asc[((size_t)tb*M_+m)*4+q]=ss; adc[((size_t)tb*M_+m)*4+q]=sd;
}

// ---------------- GAT2 softmax-aggregate + bias + relu + PE, batched ----------------
__global__ __launch_bounds__(256) void k_gat2b(
  const u16* __restrict__ h2u, const float* __restrict__ asc, const float* __restrict__ adc,
  const float* __restrict__ b2, const int* __restrict__ offs, const int* __restrict__ csr,
  float* __restrict__ seq, int t0)
{
  int tb = blockIdx.y, t = t0 + tb;
  int id = blockIdx.x*256 + threadIdx.x;
  int m = id>>2, h = id&3;
  float am = adc[((size_t)tb*M_+m)*4+h];
  int e0=offs[m], e1=offs[m+1];
  float sum=0.f;
  float A[16];
  #pragma unroll
  for(int c=0;c<16;c++) A[c]=0.f;
  for(int e=e0;e<e1;e++){
    int s=csr[e];
    float ee = asc[((size_t)tb*M_+s)*4+h] + am; ee = ee>0.f ? ee : 0.2f*ee;
    float w = __expf(ee); sum += w;
    const uint2* hp = (const uint2*)(h2u + ((size_t)tb*M_ + s)*64 + h*16);
    #pragma unroll
    for(int c2=0;c2<4;c2++){
      uint2 p = hp[c2];
      A[4*c2+0] += w*bfu((u16)(p.x));
      A[4*c2+1] += w*bfu((u16)(p.x>>16));
      A[4*c2+2] += w*bfu((u16)(p.y));
      A[4*c2+3] += w*bfu((u16)(p.y>>16));
    }
  }
  float inv = 1.f/(sum + 1e-16f);
  #pragma unroll
  for(int c=0;c<16;c++){
    int ch = h*16 + c;
    float v = A[c]*inv + b2[ch]; v = v>0.f ? v : 0.f;
    float ang = (float)t * __expf(-0.14391156463f * (float)(ch & ~1));  // ln(1e4)/64
    float pe = (ch&1) ? __cosf(ang) : __sinf(ang);
    seq[((size_t)t*M_ + m)*64 + ch] = v + pe;
  }
}

// ---------------- fused attention block: Xs/QKV LDS union, 4 blocks/CU ----------------
__global__ __launch_bounds__(256) void k_attn(
  float* __restrict__ seq,
  const u16* __restrict__ wqP,   // [16][3][64][4] packed bf16
  const u16* __restrict__ woP,   // [16][64][4]    packed bf16
  const float* __restrict__ bqkv, const float* __restrict__ bo,
  const float* __restrict__ g1,   const float* __restrict__ be1)
{
  __shared__ __align__(16) float U[4][2448];   // 39168 B total
  int tid = threadIdx.x, w = tid>>6, j = tid&63;
  int m = blockIdx.x*4 + w;
  float* Uw = U[w];

  float xr[12];
  #pragma unroll
  for(int t=0;t<12;t++){ float x = seq[((size_t)t*M_ + m)*64 + j]; xr[t]=x; Uw[t*64+j]=x; }
  float bqj = bqkv[j], bkj = bqkv[64+j], bvj = bqkv[128+j];
  float boj = bo[j], gj = g1[j], bej = be1[j];
  __syncthreads();

  // phase 1: qkv projection. lane j owns column j of q,k,v for all t.
  float q[12],k[12],v[12];
  #pragma unroll
  for(int t=0;t<12;t++){ q[t]=bqj; k[t]=bkj; v[t]=bvj; }
  const ushort4* wq4 = (const ushort4*)wqP;
  #pragma unroll
  for(int d4=0; d4<16; d4++){
    float4 xv[12];
    #pragma unroll
    for(int t=0;t<12;t++) xv[t] = *(const float4*)&Uw[t*64 + d4*4];
    ushort4 aq = wq4[(d4*3+0)*64 + j];
    ushort4 ak = wq4[(d4*3+1)*64 + j];
    ushort4 av = wq4[(d4*3+2)*64 + j];
    float q0=bfu(aq.x),q1=bfu(aq.y),q2=bfu(aq.z),q3=bfu(aq.w);
    float k0=bfu(ak.x),k1=bfu(ak.y),k2=bfu(ak.z),k3=bfu(ak.w);
    float v0=bfu(av.x),v1=bfu(av.y),v2=bfu(av.z),v3=bfu(av.w);
    #pragma unroll
    for(int t=0;t<12;t++){
      q[t]+=xv[t].x*q0; q[t]+=xv[t].y*q1; q[t]+=xv[t].z*q2; q[t]+=xv[t].w*q3;
      k[t]+=xv[t].x*k0; k[t]+=xv[t].y*k1; k[t]+=xv[t].z*k2; k[t]+=xv[t].w*k3;
      v[t]+=xv[t].x*v0; v[t]+=xv[t].y*v1; v[t]+=xv[t].z*v2; v[t]+=xv[t].w*v3;
    }
  }
  #pragma unroll
  for(int t=0;t<12;t++){
    Uw[       t*68 + j]=q[t];     // QKV[0] overlays Xs — stores depend on all loads
    Uw[ 816 + t*68 + j]=k[t];
    Uw[1632 + t*68 + j]=v[t];
  }
  __syncthreads();

  // phase 2: attention. 48 lanes own (head h, time t); in-register softmax.
  if(j < 48){
    int h = j/12, t = j - h*12;
    float* qrow = &Uw[t*68 + h*16];
    float4 a0=((float4*)qrow)[0], a1=((float4*)qrow)[1], a2=((float4*)qrow)[2], a3=((float4*)qrow)[3];
    float s[12];
    #pragma unroll
    for(int t2=0;t2<12;t2++){
      const float4* kr = (const float4*)&Uw[816 + t2*68 + h*16];
      float4 c0=kr[0], c1=kr[1], c2=kr[2], c3=kr[3];
      float d = a0.x*c0.x + a0.y*c0.y + a0.z*c0.z + a0.w*c0.w
              + a1.x*c1.x + a1.y*c1.y + a1.z*c1.z + a1.w*c1.w
              + a2.x*c2.x + a2.y*c2.y + a2.z*c2.z + a2.w*c2.w
              + a3.x*c3.x + a3.y*c3.y + a3.z*c3.z + a3.w*c3.w;
      s[t2] = d*0.25f;                 // 1/sqrt(16)
    }
    float mx = s[0];
    #pragma unroll
    for(int t2=1;t2<12;t2++) mx = fmaxf(mx, s[t2]);
    float sum = 0.f;
    #pragma unroll
    for(int t2=0;t2<12;t2++){ s[t2]=__expf(s[t2]-mx); sum+=s[t2]; }
    float inv = 1.f/sum;
    float4 o0=make_float4(0,0,0,0), o1=o0, o2=o0, o3=o0;
    #pragma unroll
    for(int t2=0;t2<12;t2++){
      const float4* vr = (const float4*)&Uw[1632 + t2*68 + h*16];
      float4 c0=vr[0], c1=vr[1], c2=vr[2], c3=vr[3];
      float ww = s[t2];
      o0.x+=ww*c0.x; o0.y+=ww*c0.y; o0.z+=ww*c0.z; o0.w+=ww*c0.w;
      o1.x+=ww*c1.x; o1.y+=ww*c1.y; o1.z+=ww*c1.z; o1.w+=ww*c1.w;
      o2.x+=ww*c2.x; o2.y+=ww*c2.y; o2.z+=ww*c2.z; o2.w+=ww*c2.w;
      o3.x+=ww*c3.x; o3.y+=ww*c3.y; o3.z+=ww*c3.z; o3.w+=ww*c3.w;
    }
    o0.x*=inv;o0.y*=inv;o0.z*=inv;o0.w*=inv;
    o1.x*=inv;o1.y*=inv;o1.z*=inv;o1.w*=inv;
    o2.x*=inv;o2.y*=inv;o2.z*=inv;o2.w*=inv;
    o3.x*=inv;o3.y*=inv;o3.z*=inv;o3.w*=inv;
    ((float4*)qrow)[0]=o0; ((float4*)qrow)[1]=o1; ((float4*)qrow)[2]=o2; ((float4*)qrow)[3]=o3;
  }
  __syncthreads();

  // phase 3: Wo + residual + LN (O sits in QKV[0] region)
  float acc[12];
  #pragma unroll
  for(int t=0;t<12;t++) acc[t]=boj;
  const ushort4* wo4 = (const ushort4*)woP;
  #pragma unroll
  for(int d4=0; d4<16; d4++){
    ushort4 aw = wo4[d4*64 + j];
    float w0=bfu(aw.x), w1=bfu(aw.y), w2=bfu(aw.z), w3=bfu(aw.w);
    #pragma unroll
    for(int t=0;t<12;t++){
      float4 ov = *(const float4*)&Uw[t*68 + d4*4];
      acc[t]+=ov.x*w0; acc[t]+=ov.y*w1; acc[t]+=ov.z*w2; acc[t]+=ov.w*w3;
    }
  }
  #pragma unroll
  for(int t=0;t<12;t++){
    float x = xr[t] + acc[t];
    float mu = wred64(x)*(1.f/64.f);
    float dd = x - mu;
    float var = wred64(dd*dd)*(1.f/64.f);
    float y = dd*rsqrtf(var+1e-5f)*gj + bej;
    seq[((size_t)t*M_ + m)*64 + j] = y;
  }
}

// ---------------- FF + residual + LN: lane-per-row, scalar-pipe weights ----------
// __launch_bounds__(256,1): relax VGPR cap so X[16]/Y[16] (128 VGPRs) stay
// register-resident (R7 spilled at the default cap=104 -> 428MB scratch writes).
// W12 interleaves w1-row||w2-row so live scalar weights peak at ~64 SGPRs.
__global__ __launch_bounds__(256,1) void k_ff(
  float* __restrict__ seq,
  const float* __restrict__ W12, const float* __restrict__ bf1,
  const float* __restrict__ bf2,
  const float* __restrict__ g2,  const float* __restrict__ be2)
{
  size_t r = (size_t)blockIdx.x*256 + threadIdx.x;   // row id; grid=1500 -> 384000 rows
  float* base = seq + r*64;

  float4 X[16], Y[16];
  #pragma unroll
  for(int i=0;i<16;i++) X[i] = ((const float4*)base)[i];
  const float4* b24 = (const float4*)bf2;
  #pragma unroll
  for(int i=0;i<16;i++) Y[i] = b24[i];

  #pragma unroll 1
  for(int hc=0;hc<128;hc++){
    const float4* w1 = (const float4*)(W12 + hc*128);        // wave-uniform -> s_load
    float s0=0.f,s1=0.f,s2=0.f,s3=0.f;
    #pragma unroll
    for(int i=0;i<16;i++){
      float4 w=w1[i];
      s0 += X[i].x*w.x; s1 += X[i].y*w.y; s2 += X[i].z*w.z; s3 += X[i].w*w.w;
    }
    float h = (s0+s1)+(s2+s3) + bf1[hc];
    h = fmaxf(h, 0.f);
    const float4* w2 = (const float4*)(W12 + hc*128 + 64);   // wave-uniform -> s_load
    #pragma unroll
    for(int i=0;i<16;i++){
      float4 w=w2[i];
      Y[i].x += h*w.x; Y[i].y += h*w.y; Y[i].z += h*w.z; Y[i].w += h*w.w;
    }
  }

  // residual + LayerNorm fully in-lane
  float s=0.f;
  #pragma unroll
  for(int i=0;i<16;i++){
    Y[i].x += X[i].x; Y[i].y += X[i].y; Y[i].z += X[i].z; Y[i].w += X[i].w;
    s += (Y[i].x+Y[i].y)+(Y[i].z+Y[i].w);
  }
  float mu = s*(1.f/64.f);
  float vs=0.f;
  #pragma unroll
  for(int i=0;i<16;i++){
    float dx=Y[i].x-mu, dy=Y[i].y-mu, dz=Y[i].z-mu, dw=Y[i].w-mu;
    vs += (dx*dx+dy*dy)+(dz*dz+dw*dw);
  }
  float sc = rsqrtf(vs*(1.f/64.f)+1e-5f);
  const float4* g4 = (const float4*)g2;
  const float4* e4 = (const float4*)be2;
  #pragma unroll
  for(int i=0;i<16;i++){
    float4 g=g4[i], bb=e4[i], o;
    o.x=(Y[i].x-mu)*sc*g.x+bb.x;
    o.y=(Y[i].y-mu)*sc*g.y+bb.y;
    o.z=(Y[i].z-mu)*sc*g.z+bb.z;
    o.w=(Y[i].w-mu)*sc*g.w+bb.w;
    ((float4*)base)[i]=o;
  }
}

// ---------------- prediction head ----------------
__global__ void k_head(const float* __restrict__ seq, const float* __restrict__ Wh,
                       const float* __restrict__ bh, float* __restrict__ out){
  int m = blockIdx.x*256 + threadIdx.x; if(m>=M_) return;
  const float* row = seq + ((size_t)11*M_ + m)*64;
  float a0=bh[0], a1=bh[1], a2=bh[2];
  #pragma unroll
  for(int d=0;d<64;d++){
    float x = row[d];
    a0 += x*Wh[d]; a1 += x*Wh[64+d]; a2 += x*Wh[128+d];
  }
  unsigned b=(unsigned)m/N_, n=(unsigned)m-b*N_;
  out[(b*3+0)*N_+n] = a0;
  out[(b*3+1)*N_+n] = a1;
  out[(b*3+2)*N_+n] = a2;
}

extern "C" void kernel_launch(void* const* d_in, const int* in_sizes, int n_in,
                              void* d_out, int out_size, void* d_ws, size_t ws_size,
                              hipStream_t stream)
{
  const float* x_seq=(const float*)d_in[0];
  const int*   ei   =(const int*)d_in[1];
  const float* W1   =(const float*)d_in[2];
  const float* as1  =(const float*)d_in[3];
  const float* ad1  =(const float*)d_in[4];
  const float* b1   =(const float*)d_in[5];
  const float* W2   =(const float*)d_in[6];
  const float* as2  =(const float*)d_in[7];
  const float* ad2  =(const float*)d_in[8];
  const float* b2   =(const float*)d_in[9];
  const float* Wqkv =(const float*)d_in[10];
  const float* bqkv =(const float*)d_in[11];
  const float* Wo   =(const float*)d_in[12];
  const float* bo   =(const float*)d_in[13];
  const float* Wf1  =(const float*)d_in[14];
  const float* bf1p =(const float*)d_in[15];
  const float* Wf2  =(const float*)d_in[16];
  const float* bf2p =(const float*)d_in[17];
  const float* g1   =(const float*)d_in[18];
  const float* be1  =(const float*)d_in[19];
  const float* g2   =(const float*)d_in[20];
  const float* be2  =(const float*)d_in[21];
  const float* Wh   =(const float*)d_in[22];
  const float* bh   =(const float*)d_in[23];

  // workspace layout (~120 MB)
  float* seq  = (float*)d_ws;            // [T][M][64]    24,576,000 f
  float* asc  = seq  + 24576000;         // [TB_][M][4]      512,000 f
  float* adc  = asc  + 512000;           //                  512,000 f
  float* W12  = adc  + 512000;           // [2][128][128]     32,768 f
  int* deg    = (int*)(W12 + 32768);
  int* cursor = deg + M_;
  int* offs   = cursor + M_;             // M_+1 used
  int* bsums  = offs + (M_ + 2);
  int* boffs  = bsums + 128;
  int* csr    = boffs + 128;             // ETOT
  u16* h2u    = (u16*)(csr + ETOT);      // [TB_][M][64]  8,192,000 u16
  u16* wqP    = h2u + (size_t)TB_*M_*64; // 24576
  u16* woP    = wqP + 24576;             // 8192

  k_prep   <<<dim3(256), dim3(256), 0, stream>>>(Wqkv, Wo, Wf1, Wf2, wqP, woP, W12);

  // CSR build (edge list identical for all t)
  k_zero   <<<dim3((2*M_+255)/256), dim3(256), 0, stream>>>(deg, 2*M_);
  k_hist   <<<dim3((ETOT+255)/256), dim3(256), 0, stream>>>(ei, deg);
  k_scan1  <<<dim3(125), dim3(256), 0, stream>>>(deg, offs, bsums);
  k_scan2  <<<dim3(1),   dim3(128), 0, stream>>>(bsums, boffs);
  k_scan3  <<<dim3(125), dim3(256), 0, stream>>>(offs, boffs);
  k_scatter<<<dim3((ETOT+255)/256), dim3(256), 0, stream>>>(ei, offs, cursor, csr);

  for(int t0=0; t0<T_; t0+=TB_){
    k_gat12<<<dim3(500,TB_), dim3(256), 0, stream>>>(x_seq, W1, as1, ad1, b1,
                                                     W2, as2, ad2, offs, csr, h2u, asc, adc, t0);
    k_gat2b<<<dim3(500,TB_), dim3(256), 0, stream>>>(h2u, asc, adc, b2, offs, csr, seq, t0);
  }

  for(int i=0;i<2;i++){
    k_attn<<<dim3(8000), dim3(256), 0, stream>>>(seq,
        wqP + (size_t)i*12288, woP + (size_t)i*4096,
        bqkv + (size_t)i*192,  bo   + (size_t)i*64,
        g1   + (size_t)i*64,   be1  + (size_t)i*64);
    k_ff  <<<dim3(1500), dim3(256), 0, stream>>>(seq,
        W12  + (size_t)i*16384, bf1p + (size_t)i*128,
        bf2p + (size_t)i*64,
        g2   + (size_t)i*64,   be2  + (size_t)i*64);
  }

  k_head<<<dim3(125), dim3(256), 0, stream>>>(seq, Wh, bh, (float*)d_out);
}